// Round 17
// baseline (537.521 us; speedup 1.0000x reference)
//
#include <hip/hip_runtime.h>
#include <hip/hip_bf16.h>
#include <cstdint>

#define BB 4
#define TT 2048
#define DD 1024
#define HH 16
#define NR (BB*TT)   /* 8192 rows */
#define CC 16        /* scan chunk length */
#define NCH (TT/CC)  /* 128 chunks */

typedef __attribute__((ext_vector_type(8))) short bf16x8;
typedef __attribute__((ext_vector_type(4))) float f32x4;
typedef __attribute__((ext_vector_type(2))) float f32x2;
typedef __attribute__((ext_vector_type(4))) unsigned int u32x4;
typedef __attribute__((ext_vector_type(2))) unsigned int u32x2;

// async global->LDS (dest = wave-uniform base + lane*SZ; src is per-lane)
#define GLL(g, l, SZ) __builtin_amdgcn_global_load_lds( \
    (const __attribute__((address_space(1))) void*)(uintptr_t)(const void*)(g), \
    (__attribute__((address_space(3))) void*)(uintptr_t)(void*)(l), SZ, 0, 0)

__device__ __forceinline__ unsigned short f2bf(float f) {
  unsigned u = __builtin_bit_cast(unsigned, f);
  unsigned r = 0x7FFFu + ((u >> 16) & 1u);
  return (unsigned short)((u + r) >> 16);
}
__device__ __forceinline__ unsigned pk2(float a, float b) {
  return (unsigned)f2bf(a) | ((unsigned)f2bf(b) << 16);
}
__device__ __forceinline__ float siluf(float v) { return v / (1.f + __expf(-v)); }
__device__ __forceinline__ float sigmf(float v) { return 1.f / (1.f + __expf(-v)); }

// ---------------- prologue: conv+silu x4 rows/block (0..2047) + weight prep ---------
__global__ __launch_bounds__(256) void prologue(
    const float* __restrict__ x,
    const float* __restrict__ qw, const float* __restrict__ qb,
    const float* __restrict__ kw, const float* __restrict__ kb,
    const float* __restrict__ vw, const float* __restrict__ vb,
    unsigned short* __restrict__ qx, unsigned short* __restrict__ kx,
    unsigned short* __restrict__ vx, unsigned short* __restrict__ xb,
    const float* __restrict__ Wq, const float* __restrict__ Wk,
    const float* __restrict__ Wv, const float* __restrict__ Wo,
    unsigned short* __restrict__ WqT, unsigned short* __restrict__ WkT,
    unsigned short* __restrict__ WvT, unsigned short* __restrict__ WoT,
    const float* __restrict__ Wau, unsigned short* __restrict__ WauT,
    const float* __restrict__ Wad, const float* __restrict__ Wgd,
    const float* __restrict__ Wbeta, unsigned short* __restrict__ Wst1T,
    const float* __restrict__ Wgu, unsigned short* __restrict__ WguT,
    const float* __restrict__ bad, const float* __restrict__ bgd,
    const float* __restrict__ bbeta, const float* __restrict__ bgu,
    float* __restrict__ bst1, float* __restrict__ bgup) {
  const int blk0 = (int)blockIdx.x;
  const int tid = threadIdx.x;
  if (blk0 < NR / 4) {
    // ---- conv + silu for 4 consecutive t rows (x rows loaded once)
    const int n0 = blk0 * 4;
    const int t0 = n0 & (TT - 1);
    const int d0 = tid * 4;
    const size_t base0 = (size_t)n0 * DD + d0;
    f32x4 zero = {0.f, 0.f, 0.f, 0.f};
    f32x4 xr[7];
#pragma unroll
    for (int i = 0; i < 7; ++i) {
      xr[i] = (t0 - 3 + i >= 0) ? *(const f32x4*)(x + base0 + (ptrdiff_t)(i - 3) * DD) : zero;
    }
    f32x4 wqv[4], wkv[4], wvv[4];
    float bq4[4], bk4[4], bv4[4];
#pragma unroll
    for (int e = 0; e < 4; ++e) {
      const int d = d0 + e;
      wqv[e] = *(const f32x4*)(qw + (size_t)d * 4);
      wkv[e] = *(const f32x4*)(kw + (size_t)d * 4);
      wvv[e] = *(const f32x4*)(vw + (size_t)d * 4);
      bq4[e] = qb[d]; bk4[e] = kb[d]; bv4[e] = vb[d];
    }
#pragma unroll
    for (int r = 0; r < 4; ++r) {
      f32x4 xm3 = xr[r], xm2 = xr[r + 1], xm1 = xr[r + 2], x0 = xr[r + 3];
      float sq[4], sk[4], sv[4];
#pragma unroll
      for (int e = 0; e < 4; ++e) {
        float aq = wqv[e][0] * xm3[e] + wqv[e][1] * xm2[e] + wqv[e][2] * xm1[e] + wqv[e][3] * x0[e] + bq4[e];
        float ak = wkv[e][0] * xm3[e] + wkv[e][1] * xm2[e] + wkv[e][2] * xm1[e] + wkv[e][3] * x0[e] + bk4[e];
        float av = wvv[e][0] * xm3[e] + wvv[e][1] * xm2[e] + wvv[e][2] * xm1[e] + wvv[e][3] * x0[e] + bv4[e];
        sq[e] = siluf(aq); sk[e] = siluf(ak); sv[e] = siluf(av);
      }
      const size_t base = base0 + (size_t)r * DD;
      u32x2 o;
      o[0] = pk2(sq[0], sq[1]); o[1] = pk2(sq[2], sq[3]); *(u32x2*)(qx + base) = o;
      o[0] = pk2(sk[0], sk[1]); o[1] = pk2(sk[2], sk[3]); *(u32x2*)(kx + base) = o;
      o[0] = pk2(sv[0], sv[1]); o[1] = pk2(sv[2], sv[3]); *(u32x2*)(vx + base) = o;
      o[0] = pk2(x0[0], x0[1]); o[1] = pk2(x0[2], x0[3]); *(u32x2*)(xb + base) = o;
    }
    return;
  }
  const int blk = blk0 - NR / 4;
  if (blk < 1024) {
    __shared__ float tile[64][65];
    const int which = blk >> 8, sub = blk & 255;
    const float* W = (which == 0) ? Wq : (which == 1) ? Wk : (which == 2) ? Wv : Wo;
    unsigned short* Wt = (which == 0) ? WqT : (which == 1) ? WkT : (which == 2) ? WvT : WoT;
    const int bk = (sub & 15) * 64, bn = (sub >> 4) * 64;
    const int r = tid >> 2, c4 = (tid & 3) * 16;
#pragma unroll 4
    for (int e = 0; e < 16; ++e)
      tile[r][c4 + e] = W[(size_t)(bk + r) * 1024 + bn + c4 + e];
    __syncthreads();
#pragma unroll 4
    for (int e = 0; e < 16; ++e)
      Wt[(size_t)(bn + r) * 1024 + bk + c4 + e] = f2bf(tile[c4 + e][r]);
  } else if (blk < 1280) {
    int idx = (blk - 1024) * 256 + tid;          // over 1024*64
    int n = idx >> 6, k = idx & 63;
    WauT[idx] = f2bf(Wau[(size_t)k * 1024 + n]);
  } else if (blk < 2304) {
    int idx = (blk - 1280) * 256 + tid;          // over 256*1024
    int n = idx >> 10, k = idx & 1023;
    float v = 0.f;
    if (n < 64) v = Wad[(size_t)k * 64 + n];
    else if (n < 128) v = Wgd[(size_t)k * 64 + (n - 64)];
    else if (n < 144) v = Wbeta[(size_t)k * 16 + (n - 128)];
    Wst1T[idx] = f2bf(v);
  } else if (blk < 2336) {
    int idx = (blk - 2304) * 256 + tid;          // over 128*64
    int n = idx >> 6, k = idx & 63;
    float v = (n < 16) ? Wgu[(size_t)k * 16 + n] : 0.f;
    WguT[idx] = f2bf(v);
  } else {
    float v = 0.f;
    if (tid < 64) v = bad[tid];
    else if (tid < 128) v = bgd[tid - 64];
    else if (tid < 144) v = bbeta[tid - 128];
    bst1[tid] = v;
    if (tid < 128) bgup[tid] = (tid < 16) ? bgu[tid] : 0.f;
  }
}

// ---------------- bf16 MFMA GEMM (A [M,K] row-major, Bt = B^T [N,K] row-major) -------
// ACT: 0 none, 1 sigmoid, 2 per-row l2norm over each 64-col head segment.
template <int ACT>
__global__ __launch_bounds__(256) void gemm_bt(
    const unsigned short* __restrict__ A, const unsigned short* __restrict__ Bt,
    const float* __restrict__ bias, float* __restrict__ C,
    int M, int N, int K, int ldc, int nstore) {
  __shared__ unsigned short lsA[128 * 32];
  __shared__ unsigned short lsB[128 * 32];
  const int tid = threadIdx.x;
  const int wid = tid >> 6, lane = tid & 63;
  const int wr = wid >> 1, wc = wid & 1;
  int bx = blockIdx.x, by = blockIdx.y;
  {
    const int nwg = gridDim.x * gridDim.y;
    if ((nwg & 7) == 0) {
      const int flat = by * gridDim.x + bx;
      const int cpx = nwg >> 3;
      const int nf = (flat & 7) * cpx + (flat >> 3);
      bx = nf % gridDim.x;
      by = nf / gridDim.x;
    }
  }
  const int m0 = bx * 128, n0 = by * 128;
  f32x4 acc[4][4] = {};
  const int nk = K >> 5;
  const int r0 = wid * 32 + (lane >> 2);
  const int cb = (lane & 3) * 16;
  char* lA = (char*)lsA;
  char* lB = (char*)lsB;
  const size_t rowb = (size_t)K * 2;

  for (int kt = 0; kt < nk; ++kt) {
    const char* gA = (const char*)(A + (size_t)(m0 + r0) * K) + kt * 64 + cb;
    const char* gB = (const char*)(Bt + (size_t)(n0 + r0) * K) + kt * 64 + cb;
    GLL(gA, lA + (wid * 32) * 64, 16);
    GLL(gA + 16 * rowb, lA + (wid * 32 + 16) * 64, 16);
    GLL(gB, lB + (wid * 32) * 64, 16);
    GLL(gB + 16 * rowb, lB + (wid * 32 + 16) * 64, 16);
    __syncthreads();
    bf16x8 af[4], bfr[4];
#pragma unroll
    for (int f = 0; f < 4; ++f)
      af[f] = *(const bf16x8*)(lA + (wr * 64 + f * 16 + (lane & 15)) * 64 + (lane >> 4) * 16);
#pragma unroll
    for (int f = 0; f < 4; ++f)
      bfr[f] = *(const bf16x8*)(lB + (wc * 64 + f * 16 + (lane & 15)) * 64 + (lane >> 4) * 16);
#pragma unroll
    for (int i = 0; i < 4; ++i)
#pragma unroll
      for (int j = 0; j < 4; ++j)
        acc[i][j] = __builtin_amdgcn_mfma_f32_16x16x32_bf16(af[i], bfr[j], acc[i][j], 0, 0, 0);
    __syncthreads();
  }

  if (ACT == 2) {
#pragma unroll
    for (int i = 0; i < 4; ++i) {
      float ss[4] = {0.f, 0.f, 0.f, 0.f};
#pragma unroll
      for (int j = 0; j < 4; ++j) {
        const int gc = n0 + wc * 64 + j * 16 + (lane & 15);
        const float bv = bias[gc];
#pragma unroll
        for (int r = 0; r < 4; ++r) {
          float v = acc[i][j][r] + bv;
          acc[i][j][r] = v;
          ss[r] = fmaf(v, v, ss[r]);
        }
      }
#pragma unroll
      for (int r = 0; r < 4; ++r) {
        float s = ss[r];
        s += __shfl_xor(s, 1);
        s += __shfl_xor(s, 2);
        s += __shfl_xor(s, 4);
        s += __shfl_xor(s, 8);
        ss[r] = 1.f / sqrtf(fmaxf(s, 1e-6f));
      }
      const int gr0 = m0 + wr * 64 + i * 16 + (lane >> 4) * 4;
#pragma unroll
      for (int j = 0; j < 4; ++j) {
        const int gc = n0 + wc * 64 + j * 16 + (lane & 15);
#pragma unroll
        for (int r = 0; r < 4; ++r)
          C[(size_t)(gr0 + r) * ldc + gc] = acc[i][j][r] * ss[r];
      }
    }
    return;
  }

#pragma unroll
  for (int i = 0; i < 4; ++i) {
    const int gr0 = m0 + wr * 64 + i * 16 + (lane >> 4) * 4;
#pragma unroll
    for (int j = 0; j < 4; ++j) {
      const int gc = n0 + wc * 64 + j * 16 + (lane & 15);
      if (gc < nstore) {
        const float bv = bias[gc];
#pragma unroll
        for (int r = 0; r < 4; ++r) {
          float v = acc[i][j][r] + bv;
          if (ACT == 1) v = sigmf(v);
          C[(size_t)(gr0 + r) * ldc + gc] = v;
        }
      }
    }
  }
}

// ---------------- stage1 GEMM with fused prep epilogue --------------------------
__global__ __launch_bounds__(256) void gemm_stage1(
    const unsigned short* __restrict__ A, const unsigned short* __restrict__ Bt,
    const float* __restrict__ bias,
    unsigned short* __restrict__ adb, unsigned short* __restrict__ gdb,
    float* __restrict__ betaT) {
  __shared__ unsigned short lsA[128 * 32];
  __shared__ unsigned short lsB[128 * 32];
  const int tid = threadIdx.x;
  const int wid = tid >> 6, lane = tid & 63;
  const int wr = wid >> 1, wc = wid & 1;
  int bx = blockIdx.x, by = blockIdx.y;
  {
    const int nwg = gridDim.x * gridDim.y;
    const int flat = by * gridDim.x + bx;
    const int cpx = nwg >> 3;
    const int nf = (flat & 7) * cpx + (flat >> 3);
    bx = nf % gridDim.x;
    by = nf / gridDim.x;
  }
  const int m0 = bx * 128, n0 = by * 128;
  const int K = 1024;
  f32x4 acc[4][4] = {};
  const int r0 = wid * 32 + (lane >> 2);
  const int cb = (lane & 3) * 16;
  char* lA = (char*)lsA;
  char* lB = (char*)lsB;
  const size_t rowb = (size_t)K * 2;

  for (int kt = 0; kt < 32; ++kt) {
    const char* gA = (const char*)(A + (size_t)(m0 + r0) * K) + kt * 64 + cb;
    const char* gB = (const char*)(Bt + (size_t)(n0 + r0) * K) + kt * 64 + cb;
    GLL(gA, lA + (wid * 32) * 64, 16);
    GLL(gA + 16 * rowb, lA + (wid * 32 + 16) * 64, 16);
    GLL(gB, lB + (wid * 32) * 64, 16);
    GLL(gB + 16 * rowb, lB + (wid * 32 + 16) * 64, 16);
    __syncthreads();
    bf16x8 af[4], bfr[4];
#pragma unroll
    for (int f = 0; f < 4; ++f)
      af[f] = *(const bf16x8*)(lA + (wr * 64 + f * 16 + (lane & 15)) * 64 + (lane >> 4) * 16);
#pragma unroll
    for (int f = 0; f < 4; ++f)
      bfr[f] = *(const bf16x8*)(lB + (wc * 64 + f * 16 + (lane & 15)) * 64 + (lane >> 4) * 16);
#pragma unroll
    for (int i = 0; i < 4; ++i)
#pragma unroll
      for (int j = 0; j < 4; ++j)
        acc[i][j] = __builtin_amdgcn_mfma_f32_16x16x32_bf16(af[i], bfr[j], acc[i][j], 0, 0, 0);
    __syncthreads();
  }

#pragma unroll
  for (int i = 0; i < 4; ++i) {
    const int gr0 = m0 + wr * 64 + i * 16 + (lane >> 4) * 4;
#pragma unroll
    for (int j = 0; j < 4; ++j) {
      const int gc = n0 + wc * 64 + j * 16 + (lane & 15);
      if (gc >= 144) continue;
      const float bv = bias[gc];
#pragma unroll
      for (int r = 0; r < 4; ++r) {
        const int row = gr0 + r;
        float v = acc[i][j][r] + bv;
        if (gc < 64) {
          adb[(size_t)row * 64 + gc] = f2bf(siluf(v));
        } else if (gc < 128) {
          gdb[(size_t)row * 64 + (gc - 64)] = f2bf(siluf(v));
        } else {
          int bb = row >> 11, tt = row & (TT - 1);
          betaT[((size_t)(bb * HH + (gc - 128))) * TT + tt] = sigmf(v);
        }
      }
    }
  }
}

// ---------------- scan Phase A v2: per-chunk WY factors (resolvent form) ------------
// (byte-identical to R16 — verified passing)
__global__ __launch_bounds__(256) void scan_phaseA(
    float* __restrict__ Qn, float* __restrict__ Kn, float* __restrict__ Vv,
    float* __restrict__ Alp, const float* __restrict__ betaT,
    float* __restrict__ Pbuf, float* __restrict__ bCbuf) {
  __shared__ float bA[CC][68], bKt[CC][68], bKp[CC][68], bQ[CC][68];
  __shared__ float bW1[CC][68], bW2[CC][68];
  __shared__ float Nm[CC][20], Nt[CC][20];
  __shared__ float Ta[CC][20], Tb[CC][20];
  __shared__ float bet[CC];
  const int bid = (int)blockIdx.x;
  const int bh = bid >> 7, c = bid & 127;
  const int b = bh >> 4, h = bh & 15;
  const int tid = threadIdx.x;
  const int tG = tid >> 4, sA = tid & 15, dG = sA * 4;
  const size_t seg = ((size_t)b * TT) * DD + h * 64;
  const size_t off = seg + (size_t)(c * CC + tG) * DD + dG;

  *(f32x4*)&bA [tG][dG] = *(const f32x4*)(Alp + off);
  *(f32x4*)&bKt[tG][dG] = *(const f32x4*)(Kn  + off);
  *(f32x4*)&bW1[tG][dG] = *(const f32x4*)(Vv  + off);
  *(f32x4*)&bQ [tG][dG] = *(const f32x4*)(Qn  + off);
  if (tid < CC) bet[tid] = betaT[(size_t)bh * TT + c * CC + tid];
  __syncthreads();

  if (tid < 64) {
    float p = bA[0][tid];
#pragma unroll
    for (int t = 1; t < CC; ++t) { p *= bA[t][tid]; bA[t][tid] = p; }
  }
  __syncthreads();

  {
    f32x4 bb = *(f32x4*)&bA[tG][dG];
    f32x4 kk = *(f32x4*)&bKt[tG][dG];
    f32x4 qq = *(f32x4*)&bQ[tG][dG];
    f32x4 vv = *(f32x4*)&bW1[tG][dG];
    f32x4 bC = *(f32x4*)&bA[CC - 1][dG];
    const float bt = bet[tG];
    f32x4 kt, kp, qt, w1, w2, kb;
#pragma unroll
    for (int e = 0; e < 4; ++e) {
      float inv = 1.0f / bb[e];
      kt[e] = kk[e] * bb[e];
      kp[e] = kk[e] * inv;
      qt[e] = qq[e] * bb[e];
      w1[e] = bt * vv[e];
      w2[e] = bt * kt[e];
      kb[e] = kp[e] * bC[e];
    }
    *(f32x4*)&bKt[tG][dG] = kt;
    *(f32x4*)&bKp[tG][dG] = kp;
    *(f32x4*)&bQ [tG][dG] = qt;
    *(f32x4*)&bW1[tG][dG] = w1;
    *(f32x4*)&bW2[tG][dG] = w2;
    *(f32x4*)(Qn + off) = qt;
    *(f32x4*)(Alp + off) = kb;
    if (tid < 64) bCbuf[((size_t)bh * 128 + c) * 64 + tid] = bA[CC - 1][tid];
  }
  __syncthreads();

  {
    f32x4 da = {0.f, 0.f, 0.f, 0.f}, dp = {0.f, 0.f, 0.f, 0.f};
#pragma unroll
    for (int ii = 0; ii < 16; ++ii) {
      f32x4 y = *(f32x4*)&bKp[sA][ii * 4];
      da += (*(f32x4*)&bKt[tG][ii * 4]) * y;
      dp += (*(f32x4*)&bQ [tG][ii * 4]) * y;
    }
    float dotA = (da[0] + da[1]) + (da[2] + da[3]);
    float dotP = (dp[0] + dp[1]) + (dp[2] + dp[3]);
    const float nval = (sA < tG) ? (-bet[tG] * dotA) : 0.f;
    Nm[tG][sA] = nval;
    Ta[tG][sA] = nval + ((sA == tG) ? 1.f : 0.f);
    Pbuf[((size_t)bh * 128 + c) * 256 + tG * 16 + sA] = (sA <= tG) ? dotP : 0.f;
  }
  __syncthreads();

  {
    float sq = 0.f;
#pragma unroll
    for (int s = 0; s < 16; ++s) sq = fmaf(Nm[tG][s], Nm[s][sA], sq);
    Nt[tG][sA] = sq;
  }
  __syncthreads();
  {
    float acc = Ta[tG][sA], sq = 0.f;
#pragma unroll
    for (int s = 0; s < 16; ++s) {
      acc = fmaf(Nt[tG][s], Ta[s][sA], acc);
      sq = fmaf(Nt[tG][s], Nt[s][sA], sq);
    }
    Tb[tG][sA] = acc;
    Nm[tG][sA] = sq;
  }
  __syncthreads();
  {
    float acc = Tb[tG][sA], sq = 0.f;
#pragma unroll
    for (int s = 0; s < 16; ++s) {
      acc = fmaf(Nm[tG][s], Tb[s][sA], acc);
      sq = fmaf(Nm[tG][s], Nm[s][sA], sq);
    }
    Ta[tG][sA] = acc;
    Nt[tG][sA] = sq;
  }
  __syncthreads();
  {
    float acc = Ta[tG][sA];
#pragma unroll
    for (int s = 0; s < 16; ++s) acc = fmaf(Nt[tG][s], Ta[s][sA], acc);
    Tb[tG][sA] = acc;
  }
  __syncthreads();
  {
    f32x4 a1 = {0.f, 0.f, 0.f, 0.f}, a2 = {0.f, 0.f, 0.f, 0.f};
    for (int s4 = 0; s4 < 4; ++s4) {
      f32x4 tv = *(f32x4*)&Tb[tG][s4 * 4];
#pragma unroll
      for (int e = 0; e < 4; ++e) {
        a1 += tv[e] * (*(f32x4*)&bW1[s4 * 4 + e][dG]);
        a2 += tv[e] * (*(f32x4*)&bW2[s4 * 4 + e][dG]);
      }
    }
    *(f32x4*)(Vv + off) = a1;
    *(f32x4*)(Kn + off) = a2;
  }
}

// ---------------- scan Phase B v6: w2/q~ direct-from-global (256 x 512) -------------
// vs v5 (same math, same sync structure): the w2 and q~ panels are no longer staged
// through LDS. Phase1 reads them straight from global — all 16 j-lanes of a T-group
// hit the same address (1 VMEM instr, L1/L2-served, sibling-XCD keeps them hot).
// Removes 16 of 24 phase1 ds_read_b128 per thread from the saturated LDS pipe.
__global__ __launch_bounds__(512, 2) void scan_phaseB(
    const float* __restrict__ W1g, const float* __restrict__ W2g,
    const float* __restrict__ Qt, const float* __restrict__ Kb,
    const float* __restrict__ Pbuf, const float* __restrict__ bCbuf,
    float* __restrict__ O, float* __restrict__ Sout) {
  __shared__ float S0T[16][68];        // [j][k] column-major state slice
  __shared__ float pU [16][17][2];     // [s][j][h]
  __shared__ float pOq[16][17][2];
  __shared__ float pkb[2][16][68];
  __shared__ float pP [2][16][20];
  __shared__ float pbC[2][64];
  const int blk = (int)blockIdx.x;
  const int bh = blk & 63, cg = blk >> 6;   // sibling-XCD remap
  const int b = bh >> 4, hh = bh & 15;
  const int tid = threadIdx.x;
  const int h = tid >> 8;          // k-half
  const int t8 = tid & 255;
  const int T = t8 >> 4, j = t8 & 15;
  const int jg = cg * 16 + j;
  const size_t seg = ((size_t)b * TT) * DD + hh * 64;

  const int qr = t8 >> 4, qc = t8 & 15;  // panel quarter row/col

#define PLOAD(c, KBR, PR, BCR, W1R)                                         \
  {                                                                         \
    if (h == 0) {                                                           \
      W1R = W1g[seg + (size_t)((c) * CC + T) * DD + jg];                    \
    } else {                                                                \
      const size_t rb = seg + (size_t)((c) * CC + qr) * DD + qc * 4;        \
      KBR = *(const f32x4*)(Kb + rb);                                       \
      PR  = Pbuf[((size_t)bh * 128 + (c)) * 256 + t8];                      \
      BCR = (t8 < 64) ? bCbuf[((size_t)bh * 128 + (c)) * 64 + t8] : 0.f;    \
    }                                                                       \
  }
#define PSTORE(bufI, KBR, PR, BCR)                                          \
  {                                                                         \
    if (h == 1) {                                                           \
      *(f32x4*)&pkb[bufI][qr][qc * 4] = KBR;                                \
      pP[bufI][qr][qc] = PR;                                                \
      if (t8 < 64) pbC[bufI][t8] = BCR;                                     \
    }                                                                       \
  }

  f32x4 kbr = {};
  float pr = 0.f, bcr = 0.f, w1l = 0.f;
  PLOAD(0, kbr, pr, bcr, w1l)
  PSTORE(0, kbr, pr, bcr)
  // zero S0T[16][0..63]: 1024 entries over 512 threads
  {
    int e0 = tid, e1 = tid + 512;
    S0T[e0 >> 6][e0 & 63] = 0.f;
    S0T[e1 >> 6][e1 & 63] = 0.f;
  }
  __syncthreads();

  for (int c = 0; c < NCH; ++c) {
    const int buf = c & 1;
    f32x4 kbn = {};
    float pn = 0.f, bcn = 0.f, w1n = 0.f;
    const bool more = (c + 1 < NCH);
    if (more) PLOAD(c + 1, kbn, pn, bcn, w1n)

    // phase1: partial U / Oq over this thread's k-half.
    // w2/q~ direct from global (broadcast within T-group), S0 via LDS b128.
    const float* w2row = W2g + seg + (size_t)(c * CC + T) * DD + h * 32;
    const float* qtrow = Qt  + seg + (size_t)(c * CC + T) * DD + h * 32;
    float u0 = (h == 0) ? w1l : 0.f, u1 = 0.f, q0 = 0.f, q1 = 0.f;
#pragma unroll
    for (int k4 = 0; k4 < 8; ++k4) {
      f32x4 wv = *(const f32x4*)(w2row + k4 * 4);
      f32x4 qv = *(const f32x4*)(qtrow + k4 * 4);
      f32x4 sv = *(const f32x4*)&S0T[j][h * 32 + k4 * 4];
      u0 = fmaf(-wv[0], sv[0], u0); q0 = fmaf(qv[0], sv[0], q0);
      u1 = fmaf(-wv[1], sv[1], u1); q1 = fmaf(qv[1], sv[1], q1);
      u0 = fmaf(-wv[2], sv[2], u0); q0 = fmaf(qv[2], sv[2], q0);
      u1 = fmaf(-wv[3], sv[3], u1); q1 = fmaf(qv[3], sv[3], q1);
    }
    pU[T][j][h] = u0 + u1;
    pOq[T][j][h] = q0 + q1;
    __syncthreads();   // partials visible; all S0 reads (phase1) done

    // um = combined U rows (b64 reads, both halves at once)
    float um[CC];
#pragma unroll
    for (int s = 0; s < CC; ++s) {
      f32x2 t2 = *(const f32x2*)&pU[s][j][0];
      um[s] = t2[0] + t2[1];
    }

    if (h == 0) {
      f32x2 oq2 = *(const f32x2*)&pOq[T][j][0];
      float o = oq2[0] + oq2[1];
#pragma unroll
      for (int s4 = 0; s4 < 4; ++s4) {
        f32x4 pv = *(const f32x4*)&pP[buf][T][s4 * 4];
        o = fmaf(pv[0], um[s4 * 4 + 0], o);
        o = fmaf(pv[1], um[s4 * 4 + 1], o);
        o = fmaf(pv[2], um[s4 * 4 + 2], o);
        o = fmaf(pv[3], um[s4 * 4 + 3], o);
      }
      O[seg + (size_t)(c * CC + T) * DD + jg] = o;
    }

    // S' rows 4T+2h, 4T+2h+1 (disjoint per thread), b64 read/modify/write
    {
      const int r0 = 4 * T + 2 * h;
      f32x2 bcv = *(const f32x2*)&pbC[buf][r0];
      f32x2 s2 = *(const f32x2*)&S0T[j][r0];
      float sp0 = bcv[0] * s2[0];
      float sp1 = bcv[1] * s2[1];
#pragma unroll
      for (int s = 0; s < CC; ++s) {
        f32x2 kv = *(const f32x2*)&pkb[buf][s][r0];
        sp0 = fmaf(kv[0], um[s], sp0);
        sp1 = fmaf(kv[1], um[s], sp1);
      }
      f32x2 so = {sp0, sp1};
      *(f32x2*)&S0T[j][r0] = so;
    }

    if (more) PSTORE(buf ^ 1, kbn, pn, bcn)
    __syncthreads();   // S0' + next panels visible
    w1l = w1n;
  }
#undef PLOAD
#undef PSTORE

  // final state [B,H,DK,DV]: each thread writes its 2 rows, its column jg
  {
    const int r0 = 4 * T + 2 * h;
    f32x2 s2 = *(const f32x2*)&S0T[j][r0];
    Sout[(size_t)bh * 4096 + (size_t)(r0 + 0) * 64 + jg] = s2[0];
    Sout[(size_t)bh * 4096 + (size_t)(r0 + 1) * 64 + jg] = s2[1];
  }
}

// ---------------- headwise RMSNorm * rms_w * gate -> bf16 ----------------
__global__ __launch_bounds__(256) void rms_gate(
    const float* __restrict__ O, const float* __restrict__ rmsw,
    const float* __restrict__ gate, unsigned short* __restrict__ Og) {
  const int tid = threadIdx.x;
  const int row = blockIdx.x * 4 + (tid >> 6);
  const int lane = tid & 63;
  const int h = lane >> 2;
  const float* p = O + (size_t)row * DD + lane * 16;
  f32x4 v[4];
  float ss = 0.f;
#pragma unroll
  for (int u = 0; u < 4; ++u) {
    v[u] = *(const f32x4*)(p + u * 4);
#pragma unroll
    for (int e = 0; e < 4; ++e) ss = fmaf(v[u][e], v[u][e], ss);
  }
  ss += __shfl_xor(ss, 1);
  ss += __shfl_xor(ss, 2);
  const float rs = rsqrtf(ss * (1.f / 64.f) + 1e-6f);
  const float g = gate[row * 16 + h];
  const float* wp = rmsw + h * 64 + (lane & 3) * 16;
  unsigned ow[8];
#pragma unroll
  for (int u = 0; u < 4; ++u) {
    f32x4 wv = *(const f32x4*)(wp + u * 4);
    float a0 = v[u][0] * rs * wv[0] * g, a1 = v[u][1] * rs * wv[1] * g;
    float a2 = v[u][2] * rs * wv[2] * g, a3 = v[u][3] * rs * wv[3] * g;
    ow[u * 2] = pk2(a0, a1);
    ow[u * 2 + 1] = pk2(a2, a3);
  }
  u32x4* dst = (u32x4*)(Og + (size_t)row * DD + lane * 16);
  u32x4 o1, o2;
  o1[0] = ow[0]; o1[1] = ow[1]; o1[2] = ow[2]; o1[3] = ow[3];
  o2[0] = ow[4]; o2[1] = ow[5]; o2[2] = ow[6]; o2[3] = ow[7];
  dst[0] = o1; dst[1] = o2;
}

// ---------------- launch ----------------
extern "C" void kernel_launch(void* const* d_in, const int* in_sizes, int n_in,
                              void* d_out, int out_size, void* d_ws, size_t ws_size,
                              hipStream_t stream) {
  const float* x    = (const float*)d_in[0];
  const float* qw   = (const float*)d_in[1];
  const float* qb   = (const float*)d_in[2];
  const float* kw   = (const float*)d_in[3];
  const float* kb   = (const float*)d_in[4];
  const float* vw   = (const float*)d_in[5];
  const float* vb   = (const float*)d_in[6];
  const float* Wq   = (const float*)d_in[7];
  const float* bq   = (const float*)d_in[8];
  const float* Wk   = (const float*)d_in[9];
  const float* bk   = (const float*)d_in[10];
  const float* Wv   = (const float*)d_in[11];
  const float* bv   = (const float*)d_in[12];
  const float* Wad  = (const float*)d_in[13];
  const float* bad  = (const float*)d_in[14];
  const float* Wau  = (const float*)d_in[15];
  const float* bau  = (const float*)d_in[16];
  const float* Wbeta= (const float*)d_in[17];
  const float* bbeta= (const float*)d_in[18];
  const float* rmsw = (const float*)d_in[19];
  const float* Wgd  = (const float*)d_in[20];
  const float* bgd  = (const float*)d_in[21];
  const float* Wgu  = (const float*)d_in[22];
  const float* bgu  = (const float*)d_in[23];
  const float* Wo   = (const float*)d_in[24];
  const float* bo   = (const float*)d_in[25];

  char* ws = (char*)d_ws;
  const size_t MB = 1ull << 20;
  unsigned short* WqT   = (unsigned short*)(ws + 0 * MB);
  unsigned short* WkT   = (unsigned short*)(ws + 2 * MB);
  unsigned short* WvT   = (unsigned short*)(ws + 4 * MB);
  unsigned short* WoT   = (unsigned short*)(ws + 6 * MB);
  unsigned short* WauT  = (unsigned short*)(ws + 8 * MB);
  unsigned short* Wst1T = (unsigned short*)(ws + 8 * MB + 256 * 1024);
  unsigned short* WguT  = (unsigned short*)(ws + 8 * MB + 768 * 1024);
  float* bst1 = (float*)(ws + 8 * MB + 800 * 1024);
  float* bgup = (float*)(ws + 8 * MB + 804 * 1024);
  unsigned short* x_bf = (unsigned short*)(ws + 9 * MB);
  unsigned short* qx   = (unsigned short*)(ws + 25 * MB);
  unsigned short* kx   = (unsigned short*)(ws + 41 * MB);
  unsigned short* vx   = (unsigned short*)(ws + 57 * MB);
  float* Qn    = (float*)(ws + 73 * MB);
  float* Kn    = (float*)(ws + 105 * MB);
  float* Vv    = (float*)(ws + 137 * MB);
  float* stage1= (float*)(ws + 169 * MB);
  unsigned short* adb = (unsigned short*)(ws + 177 * MB);
  unsigned short* gdb = (unsigned short*)(ws + 178 * MB);
  float* betaT = (float*)(ws + 179 * MB);
  float* gate  = (float*)(ws + 179 * MB + 512 * 1024);
  float* bCbuf = (float*)(ws + 180 * MB);           // 2MB
  // reuse (order-safe): alpha over x_bf+qx, O over kx+vx, Og over V, Pbuf over stage1
  float* alpha = (float*)(ws + 9 * MB);
  float* Obuf  = (float*)(ws + 41 * MB);
  unsigned short* Og = (unsigned short*)(ws + 137 * MB);
  float* Pbuf  = stage1;
  float* y = (float*)d_out;
  float* Sout = y + (size_t)NR * DD;

  dim3 blk(256);
  prologue<<<dim3(NR / 4 + 2337), blk, 0, stream>>>(
      x, qw, qb, kw, kb, vw, vb, qx, kx, vx, x_bf,
      Wq, Wk, Wv, Wo, WqT, WkT, WvT, WoT,
      Wau, WauT, Wad, Wgd, Wbeta, Wst1T, Wgu, WguT,
      bad, bgd, bbeta, bgu, bst1, bgup);

  gemm_stage1<<<dim3(64, 2), blk, 0, stream>>>(x_bf, Wst1T, bst1, adb, gdb, betaT);
  gemm_bt<2><<<dim3(64, 8), blk, 0, stream>>>(qx, WqT, bq, Qn, NR, 1024, 1024, 1024, 1024);
  gemm_bt<2><<<dim3(64, 8), blk, 0, stream>>>(kx, WkT, bk, Kn, NR, 1024, 1024, 1024, 1024);
  gemm_bt<0><<<dim3(64, 8), blk, 0, stream>>>(vx, WvT, bv, Vv, NR, 1024, 1024, 1024, 1024);
  gemm_bt<1><<<dim3(64, 8), blk, 0, stream>>>(adb, WauT, bau, alpha, NR, 1024, 64, 1024, 1024);
  gemm_bt<1><<<dim3(64, 1), blk, 0, stream>>>(gdb, WguT, bgup, gate, NR, 128, 64, 16, 16);

  scan_phaseA<<<dim3(8192), blk, 0, stream>>>(Qn, Kn, Vv, alpha, betaT, Pbuf, bCbuf);
  scan_phaseB<<<dim3(256), dim3(512), 0, stream>>>(Vv, Kn, Qn, alpha, Pbuf, bCbuf, Obuf, Sout);

  rms_gate<<<dim3(2048), blk, 0, stream>>>(Obuf, rmsw, gate, Og);
  gemm_bt<0><<<dim3(64, 8), blk, 0, stream>>>(Og, WoT, bo, y, NR, 1024, 1024, 1024, 1024);
}